// Round 8
// baseline (2442.946 us; speedup 1.0000x reference)
//
#include <hip/hip_runtime.h>
#include <cstdint>
#include <cstddef>

#define NSTEPS 30

typedef __attribute__((ext_vector_type(4))) float f32x4;
typedef __attribute__((ext_vector_type(8))) short bf16x8;

__device__ __forceinline__ unsigned short f2bf(float f) {
  union { float f; unsigned int u; } v; v.f = f;
  return (unsigned short)((v.u + 0x7FFFu + ((v.u >> 16) & 1u)) >> 16);
}
__device__ __forceinline__ float bf2f(unsigned short u) {
  union { unsigned int u; float f; } v; v.u = ((unsigned int)u) << 16;
  return v.f;
}

__device__ __forceinline__ void gload_lds16(const void* g, void* l) {
  __builtin_amdgcn_global_load_lds(
      (const __attribute__((address_space(1))) unsigned int*)g,
      (__attribute__((address_space(3))) unsigned int*)l, 16, 0, 0);
}

// ---------------------------------------------------------------------------
// 256x128-tile GEMM, BK=64, 3-buffer counted-vmcnt, XCD swizzle, XOR-swizzled
// LDS: C = A @ B^T.  4 waves (2M x 2N), per-wave 128x64 output = 8x4 frags of
// mfma 16x16x32 bf16 (m201 per-wave shape: 64 MFMA : 24 ds_read per K-tile).
// LDS 144 KiB: A tri-buf [256][64] + B tri-buf [128][64].
// Pipeline per K-tile t: vmcnt(12) [retire t; t+1 in flight] -> barrier ->
// stage t+2 into buf[(t+2)%3] -> ds_read + 64 MFMA on buf[t%3].
// MODE 0: xpb = bf16(acc*is + bias + bias2); outbf2 = bf16(tanh(same))
// MODE 1: outbf = bf16(tanh(acc*is + xpb))
// MODE 2: if c<Nreal: outf[r*Nreal+c] = acc*is + bias[c]
// MODE 3: outbf = bf16(acc)            (H = W @ W^T build; no scale/bias)
// ---------------------------------------------------------------------------
template <int MODE>
__global__ __launch_bounds__(256, 1) void gemm3b(
    const unsigned short* __restrict__ A, const unsigned short* __restrict__ Bm,
    int N, int K, int nbm, int nbn, const float* __restrict__ bias,
    const float* __restrict__ bias2, const unsigned short* __restrict__ xpb,
    const float* __restrict__ inv_sig, float* __restrict__ outf,
    unsigned short* __restrict__ outbf, unsigned short* __restrict__ outbf2,
    int Nreal) {
  __shared__ short lds[73728];  // 144 KiB: A 3x16384, B 3x8192 (shorts)
  const int t = threadIdx.x, w = t >> 6, l = t & 63;
  const int wm = w >> 1, wn = w & 1;  // 2M x 2N wave grid
  // XCD swizzle: 4x2 XCD grid; per-XCD contiguous (nbm/4)x(nbn/2) region.
  const int nbn2 = nbn >> 1, nbm4 = nbm >> 2;
  const int xcd = blockIdx.x & 7, q = blockIdx.x >> 3;
  const int bm = (xcd >> 1) * nbm4 + q / nbn2;
  const int bn = (xcd & 1) * nbn2 + q % nbn2;
  const int row0 = bm << 8, col0 = bn << 7;
  const int NKT = K >> 6;

  f32x4 acc[8][4];
#pragma unroll
  for (int i = 0; i < 8; ++i)
#pragma unroll
    for (int j = 0; j < 4; ++j) acc[i][j] = (f32x4){0.f, 0.f, 0.f, 0.f};

  // Stage K-tile `tile` into buffer `buf` (0..2). 12 gload_lds16 per thread
  // (A 8, B 4). Dest linear: row*128B + (l&7)*16B (= base + lane*16B).
  // Source k pre-swizzled by ((row&7)<<4) bytes; row&7 == l>>3.
#define STAGE(tile, buf)                                                      \
  do {                                                                        \
    const int kt_ = (tile) << 6;                                              \
    const int kb_ = (((l & 7) ^ (l >> 3)) << 4) >> 1; /* shorts */            \
    const int rl_ = w * 8 + (l >> 3);                                         \
    _Pragma("unroll") for (int j_ = 0; j_ < 8; ++j_) {                        \
      gload_lds16(A + (size_t)(row0 + j_ * 32 + rl_) * K + kt_ + kb_,         \
                  lds + (buf) * 16384 + j_ * 2048 + w * 512);                 \
    }                                                                         \
    _Pragma("unroll") for (int j_ = 0; j_ < 4; ++j_) {                        \
      gload_lds16(Bm + (size_t)(col0 + j_ * 32 + rl_) * K + kt_ + kb_,        \
                  lds + 49152 + (buf) * 8192 + j_ * 2048 + w * 512);          \
    }                                                                         \
  } while (0)

  STAGE(0, 0);
  STAGE(1, 1);

  const int ar = l & 15;
  const int swzk = (l & 7) << 4;               // bytes
  const int klo = (l >> 4) << 4;               // bytes
  const int kb0 = ((klo ^ swzk) >> 1);         // shorts, k-slice 0
  const int kb1 = (((klo + 64) ^ swzk) >> 1);  // shorts, k-slice 1

  int cur = 0;
  for (int kt = 0; kt < NKT; ++kt) {
    if (kt + 1 < NKT) {
      asm volatile("s_waitcnt vmcnt(12)" ::: "memory");
    } else {
      asm volatile("s_waitcnt vmcnt(0)" ::: "memory");
    }
    __builtin_amdgcn_s_barrier();
    __builtin_amdgcn_sched_barrier(0);
    if (kt + 2 < NKT) {
      const int stg = (cur >= 1) ? cur - 1 : cur + 2;  // (cur+2)%3
      STAGE(kt + 2, stg);
    }

    const int abase = cur * 16384 + (wm * 128 + ar) * 64;
    const int bbase = 49152 + cur * 8192 + (wn * 64 + ar) * 64;
    bf16x8 bv[4][2];
#pragma unroll
    for (int fn = 0; fn < 4; ++fn) {
      bv[fn][0] = *(const bf16x8*)(lds + bbase + fn * 1024 + kb0);
      bv[fn][1] = *(const bf16x8*)(lds + bbase + fn * 1024 + kb1);
    }
#pragma unroll
    for (int s = 0; s < 2; ++s) {
#pragma unroll
      for (int fm = 0; fm < 8; ++fm) {
        const bf16x8 av = *(const bf16x8*)(lds + abase + fm * 1024 +
                                           (s ? kb1 : kb0));
#pragma unroll
        for (int fn = 0; fn < 4; ++fn)
          acc[fm][fn] = __builtin_amdgcn_mfma_f32_16x16x32_bf16(
              av, bv[fn][s], acc[fm][fn], 0, 0, 0);
      }
    }
    cur = (cur == 2) ? 0 : cur + 1;
  }
#undef STAGE

  const float is = (MODE == 3) ? 1.0f : inv_sig[0];
#pragma unroll
  for (int fm = 0; fm < 8; ++fm) {
#pragma unroll
    for (int fn = 0; fn < 4; ++fn) {
      const int c = col0 + wn * 64 + fn * 16 + ar;
#pragma unroll
      for (int qq = 0; qq < 4; ++qq) {
        const int r = row0 + wm * 128 + fm * 16 + (l >> 4) * 4 + qq;
        const float v = acc[fm][fn][qq] * is;
        if (MODE == 0) {
          const float vv = v + bias[c] + bias2[c];
          outbf[(size_t)r * N + c] = f2bf(vv);
          outbf2[(size_t)r * N + c] = f2bf(tanhf(vv));
        } else if (MODE == 1) {
          outbf[(size_t)r * N + c] =
              f2bf(tanhf(v + bf2f(xpb[(size_t)r * N + c])));
        } else if (MODE == 2) {
          if (c < Nreal) outf[(size_t)r * Nreal + c] = v + bias[c];
        } else {
          outbf[(size_t)r * N + c] = f2bf(v);
        }
      }
    }
  }
}

// ---------------------------------------------------------------------------
// Fused f32 -> bf16 convert + transpose with row padding:
//   outN[Rpad][C] = bf16(in) (pad rows 0);  outT[C][Rpad] = bf16(in^T).
// ---------------------------------------------------------------------------
__global__ __launch_bounds__(256) void convT_b(const float* __restrict__ in,
                                               unsigned short* __restrict__ outN,
                                               unsigned short* __restrict__ outT,
                                               int Rpad, int C, int Rreal) {
  __shared__ float tile[32][33];
  const int c0 = blockIdx.x * 32, r0 = blockIdx.y * 32;
  const int tx = threadIdx.x & 31, ty = threadIdx.x >> 5;
  for (int i = ty; i < 32; i += 8) {
    const int r = r0 + i;
    const float v = (r < Rreal) ? in[(size_t)r * C + (c0 + tx)] : 0.f;
    outN[(size_t)r * C + (c0 + tx)] = f2bf(v);
    tile[i][tx] = v;
  }
  __syncthreads();
  for (int i = ty; i < 32; i += 8) {
    outT[(size_t)(c0 + i) * Rpad + (r0 + tx)] = f2bf(tile[tx][i]);
  }
}

// Row-dot helpers
__device__ __forceinline__ float dot_bf(const unsigned short* Mr,
                                        const float* xv, int dot, int l) {
  float s = 0.f;
#pragma unroll 4
  for (int j = l * 8; j < dot; j += 512) {
    const bf16x8 mv = *(const bf16x8*)(Mr + j);
    const float4 xa = *(const float4*)(xv + j);
    const float4 xb = *(const float4*)(xv + j + 4);
    s += bf2f((unsigned short)mv[0]) * xa.x + bf2f((unsigned short)mv[1]) * xa.y +
         bf2f((unsigned short)mv[2]) * xa.z + bf2f((unsigned short)mv[3]) * xa.w +
         bf2f((unsigned short)mv[4]) * xb.x + bf2f((unsigned short)mv[5]) * xb.y +
         bf2f((unsigned short)mv[6]) * xb.z + bf2f((unsigned short)mv[7]) * xb.w;
  }
  return s;
}
__device__ __forceinline__ float dot_f32(const float* Mr, const float* xv,
                                         int dot, int l) {
  float s = 0.f;
#pragma unroll 8
  for (int j = l * 4; j < dot; j += 256) {
    const float4 mv = *(const float4*)(Mr + j);
    const float4 xv4 = *(const float4*)(xv + j);
    s += mv.x * xv4.x + mv.y * xv4.y + mv.z * xv4.z + mv.w * xv4.w;
  }
  return s;
}
__device__ __forceinline__ float wave_red(float s) {
#pragma unroll
  for (int off = 32; off; off >>= 1) s += __shfl_down(s, off, 64);
  return s;
}

// fp32 matvec (sigma pass, exact weights): y[r] = mulv[r] * (row_r(M) . x)
struct MatDesc {
  const float* M;
  const float* x;
  float* y;
  const float* mulv;
  int rows, ld, dot, rreal;
};

__global__ __launch_bounds__(256) void matvec3(MatDesc d0, MatDesc d1,
                                               MatDesc d2, int n0, int n1) {
  int b = blockIdx.x;
  MatDesc d;
  if (b < n0) d = d0;
  else if (b < n0 + n1) { d = d1; b -= n0; }
  else { d = d2; b -= n0 + n1; }
  const int w = threadIdx.x >> 6, l = threadIdx.x & 63;
  const int r = b * 4 + w;
  if (r >= d.rows) return;
  float s = (r < d.rreal) ? dot_f32(d.M + (size_t)r * d.ld, d.x, d.dot, l) : 0.f;
  s = wave_red(s);
  if (l == 0) d.y[r] = (d.mulv ? d.mulv[r] : 1.f) * s;
}

// bf16 matvec (power-iteration passes): y[r] = row_r(M) . x
struct MatDescB {
  const unsigned short* M;
  const float* x;
  float* y;
  int rows, ld, dot;
};

__global__ __launch_bounds__(256) void matvec3b(MatDescB d0, MatDescB d1,
                                                MatDescB d2, int n0, int n1) {
  int b = blockIdx.x;
  MatDescB d;
  if (b < n0) d = d0;
  else if (b < n0 + n1) { d = d1; b -= n0; }
  else { d = d2; b -= n0 + n1; }
  const int w = threadIdx.x >> 6, l = threadIdx.x & 63;
  const int r = b * 4 + w;
  if (r >= d.rows) return;
  float s = dot_bf(d.M + (size_t)r * d.ld, d.x, d.dot, l);
  s = wave_red(s);
  if (l == 0) d.y[r] = s;
}

__global__ void init_p(float* p) {
  const int i = blockIdx.x * 256 + threadIdx.x;
  if (i < 5120) p[i] = (i < 5096) ? 1.f : 0.f;  // p_out rows 1000..1023 = 0
}

// Single-block deterministic reductions -> inv_sigma[3]
__global__ __launch_bounds__(256) void finalize_sigma(
    const float* __restrict__ p, const float* __restrict__ t,
    const float* __restrict__ cb, float* __restrict__ scal) {
  __shared__ float red[256];
  __shared__ float sres[9];
  const int segs[9][2] = {{0, 2048},    {2048, 2048}, {4096, 1024},
                          {0, 1024},    {1024, 2048}, {3072, 2048},
                          {0, 2048},    {2048, 2048}, {4096, 1024}};
  const float* bases[3] = {p, t, cb};
  for (int s = 0; s < 9; ++s) {
    const float* src = bases[s / 3] + segs[s][0];
    const int len = segs[s][1];
    float acc = 0.f;
    for (int i = threadIdx.x; i < len; i += 256) {
      const float v = src[i];
      acc += (s < 6) ? v * v : v;
    }
    red[threadIdx.x] = acc;
    __syncthreads();
    for (int st = 128; st; st >>= 1) {
      if (threadIdx.x < st) red[threadIdx.x] += red[threadIdx.x + st];
      __syncthreads();
    }
    if (threadIdx.x == 0) sres[s] = red[0];
    __syncthreads();
  }
  if (threadIdx.x == 0) {
    const float eps = 1e-12f;
    for (int m = 0; m < 3; ++m) {
      const float np = sqrtf(sres[m]);
      const float nt = sqrtf(sres[3 + m]);
      const float sig = sres[6 + m] / ((np + eps) * (nt + eps));
      scal[m] = 1.0f / sig;
    }
  }
}

// fp32 -> bf16 (x only)
__global__ __launch_bounds__(256) void f32_to_bf16_pad(
    const float* __restrict__ src, unsigned short* __restrict__ dst,
    long realTotal, long total) {
  const long idx = ((long)blockIdx.x * 256 + threadIdx.x) * 4;
  if (idx >= total) return;
  ushort4 o;
  if (idx < realTotal) {
    const float4 v = *(const float4*)(src + idx);
    o.x = f2bf(v.x); o.y = f2bf(v.y); o.z = f2bf(v.z); o.w = f2bf(v.w);
  } else {
    o.x = o.y = o.z = o.w = 0;
  }
  *(ushort4*)(dst + idx) = o;
}

// ---------------------------------------------------------------------------
extern "C" void kernel_launch(void* const* d_in, const int* in_sizes, int n_in,
                              void* d_out, int out_size, void* d_ws,
                              size_t ws_size, hipStream_t stream) {
  const float* x = (const float*)d_in[0];
  const float* W_in = (const float*)d_in[1];
  const float* b_in = (const float*)d_in[2];
  const float* W_rec = (const float*)d_in[3];
  const float* b_rec = (const float*)d_in[4];
  const float* W_out = (const float*)d_in[5];
  const float* b_out = (const float*)d_in[6];
  (void)in_sizes; (void)n_in; (void)out_size; (void)ws_size;

  const int B = 4096, DI = 1024, H = 2048, DO = 1000, DOP = 1024;
  const long MB = 1l << 20;

  char* ws = (char*)d_ws;
  unsigned short* Win_bf = (unsigned short*)(ws + 0 * MB);    // [2048][1024] 4MB
  unsigned short* Wrec_bf = (unsigned short*)(ws + 4 * MB);   // [2048][2048] 8MB
  unsigned short* Wout_bf = (unsigned short*)(ws + 12 * MB);  // [1024][2048] 4MB
  unsigned short* x_bf = (unsigned short*)(ws + 16 * MB);     // [4096][1024] 8MB
  unsigned short* xpb = (unsigned short*)(ws + 24 * MB);      // [4096][2048] 16MB
  // WT region (40..56MB) dead after the final W^T pass; h_a aliases it.
  unsigned short* WT_in_bf = (unsigned short*)(ws + 40 * MB);   // 4MB
  unsigned short* WT_rec_bf = (unsigned short*)(ws + 44 * MB);  // 8MB
  unsigned short* WT_out_bf = (unsigned short*)(ws + 52 * MB);  // 4MB
  unsigned short* h_a = (unsigned short*)(ws + 40 * MB);      // 16MB (alias WT)
  // H region (56..74MB) dead after the 30 H-passes; h_b aliases 56..72MB.
  unsigned short* H_in = (unsigned short*)(ws + 56 * MB);     // [2048][2048] 8MB
  unsigned short* H_rec = (unsigned short*)(ws + 64 * MB);    // [2048][2048] 8MB
  unsigned short* H_out = (unsigned short*)(ws + 72 * MB);    // [1024][1024] 2MB
  unsigned short* h_b = (unsigned short*)(ws + 56 * MB);      // 16MB (alias H)
  float* pvec = (float*)(ws + 76 * MB);
  float* tvec = pvec + 5120;
  float* cbuf = tvec + 5120;
  float* scal = cbuf + 5120;
  float* qvec = scal + 16;

  float* p_in = pvec, *p_rec = pvec + 2048, *p_out = pvec + 4096;
  float* t_in = tvec, *t_rec = tvec + 1024, *t_out = tvec + 3072;
  float* q_in = qvec, *q_rec = qvec + 2048, *q_out = qvec + 4096;

  // 1. Fused convert+transpose for weights; x convert.
  convT_b<<<dim3(DI / 32, H / 32), 256, 0, stream>>>(W_in, Win_bf, WT_in_bf,
                                                     H, DI, H);
  convT_b<<<dim3(H / 32, H / 32), 256, 0, stream>>>(W_rec, Wrec_bf, WT_rec_bf,
                                                    H, H, H);
  convT_b<<<dim3(H / 32, DOP / 32), 256, 0, stream>>>(W_out, Wout_bf,
                                                      WT_out_bf, DOP, H, DO);
  f32_to_bf16_pad<<<4096, 256, 0, stream>>>(x, x_bf, (long)B * DI, (long)B * DI);

  // 2a. H = bf16(W @ W^T) per matrix (MFMA GEMM, MODE 3).
  init_p<<<20, 256, 0, stream>>>(pvec);
  gemm3b<3><<<8 * 16, 256, 0, stream>>>(Win_bf, Win_bf, H, DI, 8, 16, nullptr,
                                        nullptr, nullptr, nullptr, nullptr,
                                        H_in, nullptr, H);
  gemm3b<3><<<8 * 16, 256, 0, stream>>>(Wrec_bf, Wrec_bf, H, H, 8, 16, nullptr,
                                        nullptr, nullptr, nullptr, nullptr,
                                        H_rec, nullptr, H);
  gemm3b<3><<<4 * 8, 256, 0, stream>>>(Wout_bf, Wout_bf, DOP, H, 4, 8, nullptr,
                                       nullptr, nullptr, nullptr, nullptr,
                                       H_out, nullptr, DOP);

  // 2b. 30 passes of u <- H u (ping-pong p <-> q), one fused launch each.
  MatDescB HpA = {H_in, p_in, q_in, 2048, 2048, 2048};
  MatDescB HpB = {H_rec, p_rec, q_rec, 2048, 2048, 2048};
  MatDescB HpC = {H_out, p_out, q_out, 1024, 1024, 1024};
  MatDescB HqA = {H_in, q_in, p_in, 2048, 2048, 2048};
  MatDescB HqB = {H_rec, q_rec, p_rec, 2048, 2048, 2048};
  MatDescB HqC = {H_out, q_out, p_out, 1024, 1024, 1024};
  for (int it = 0; it < NSTEPS / 2; ++it) {
    matvec3b<<<1280, 256, 0, stream>>>(HpA, HpB, HpC, 512, 512);
    matvec3b<<<1280, 256, 0, stream>>>(HqA, HqB, HqC, 512, 512);
  }
  // final: t = W^T u  (v unnormalized)
  MatDescB B1a = {WT_in_bf, p_in, t_in, 1024, 2048, 2048};
  MatDescB B1b = {WT_rec_bf, p_rec, t_rec, 2048, 2048, 2048};
  MatDescB B1c = {WT_out_bf, p_out, t_out, 2048, 1024, 1024};
  matvec3b<<<1280, 256, 0, stream>>>(B1a, B1b, B1c, 256, 512);

  // 3. sigma via exact fp32 W: c_i = p_i * (row_i(W) . t); then 1/sigma
  MatDesc sa = {W_in, t_in, cbuf, p_in, 2048, 1024, 1024, 2048};
  MatDesc sb = {W_rec, t_rec, cbuf + 2048, p_rec, 2048, 2048, 2048, 2048};
  MatDesc sc = {W_out, t_out, cbuf + 4096, p_out, 1024, 2048, 2048, 1000};
  matvec3<<<1280, 256, 0, stream>>>(sa, sb, sc, 512, 512);
  finalize_sigma<<<1, 256, 0, stream>>>(pvec, tvec, cbuf, scal);

  // 4. xpb = bf16(x @ Win^T * is0 + b_in + b_rec); h1 = tanh(same), fused
  gemm3b<0><<<16 * 16, 256, 0, stream>>>(
      x_bf, Win_bf, H, DI, 16, 16, b_in, b_rec, nullptr, scal + 0, nullptr,
      xpb, h_a, H);

  // 5. 29 recurrent GEMM steps ping-pong
  const unsigned short* hin = h_a;
  unsigned short* hout = h_b;
  for (int s = 2; s <= NSTEPS; ++s) {
    gemm3b<1><<<16 * 16, 256, 0, stream>>>(
        hin, Wrec_bf, H, H, 16, 16, nullptr, nullptr, xpb, scal + 1, nullptr,
        hout, nullptr, H);
    const unsigned short* tmp = hin;
    hin = hout;
    hout = (unsigned short*)tmp;
  }

  // 6. out = h @ Wout^T * is2 + b_out  (N padded to 1024, stores guarded)
  gemm3b<2><<<16 * 8, 256, 0, stream>>>(
      hin, Wout_bf, DOP, H, 16, 8, b_out, nullptr, nullptr, scal + 2,
      (float*)d_out, nullptr, nullptr, DO);
}

// Round 9
// 1684.697 us; speedup vs baseline: 1.4501x; 1.4501x over previous
//
#include <hip/hip_runtime.h>
#include <cstdint>
#include <cstddef>

#define NSTEPS 30

typedef __attribute__((ext_vector_type(4))) float f32x4;
typedef __attribute__((ext_vector_type(8))) short bf16x8;

__device__ __forceinline__ unsigned short f2bf(float f) {
  union { float f; unsigned int u; } v; v.f = f;
  return (unsigned short)((v.u + 0x7FFFu + ((v.u >> 16) & 1u)) >> 16);
}
__device__ __forceinline__ float bf2f(unsigned short u) {
  union { unsigned int u; float f; } v; v.u = ((unsigned int)u) << 16;
  return v.f;
}

__device__ __forceinline__ void gload_lds16(const void* g, void* l) {
  __builtin_amdgcn_global_load_lds(
      (const __attribute__((address_space(1))) unsigned int*)g,
      (__attribute__((address_space(3))) unsigned int*)l, 16, 0, 0);
}

// ---------------------------------------------------------------------------
// 128x128-tile GEMM, BK=64, double-buffered 2-phase, 2 blocks/CU: C = A @ B^T.
// 4 waves (2M x 2N), per-wave 64x64 = 4x4 frags of mfma 16x16x32 bf16.
// LDS 64 KiB: A dbuf [128][64] + B dbuf [128][64], XOR-swizzled
// (byte ^= (row&7)<<4; inverse-swizzled GLOBAL source + linear
// global_load_lds dest + swizzled ds_read). Per K-tile: STAGE(t+1 -> buf^1);
// compute(buf); __syncthreads(). Barrier drain per tile is covered by the
// co-resident second block per CU (inter-block overlap, m97 mechanism).
// XCD swizzle: xcd=bid&7 -> 4x2 XCD grid; per-XCD (nbm/4)x(nbn/2) region.
// MODE 0: xpb = bf16(acc*is + bias + bias2); outbf2 = bf16(tanh(same))
// MODE 1: outbf = bf16(tanh(acc*is + xpb))
// MODE 2: if c<Nreal: outf[r*Nreal+c] = acc*is + bias[c]
// MODE 3: outbf = bf16(acc)            (H = W @ W^T build; no scale/bias)
// ---------------------------------------------------------------------------
template <int MODE>
__global__ __launch_bounds__(256, 2) void gemm3b(
    const unsigned short* __restrict__ A, const unsigned short* __restrict__ Bm,
    int N, int K, int nbm, int nbn, const float* __restrict__ bias,
    const float* __restrict__ bias2, const unsigned short* __restrict__ xpb,
    const float* __restrict__ inv_sig, float* __restrict__ outf,
    unsigned short* __restrict__ outbf, unsigned short* __restrict__ outbf2,
    int Nreal) {
  __shared__ short lds[32768];  // 64 KiB: A 2x8192, B 2x8192 (shorts)
  const int t = threadIdx.x, w = t >> 6, l = t & 63;
  const int wm = w >> 1, wn = w & 1;  // 2M x 2N wave grid
  // XCD swizzle: 4x2 XCD grid; per-XCD contiguous (nbm/4)x(nbn/2) region.
  const int nbn2 = nbn >> 1, nbm4 = nbm >> 2;
  const int xcd = blockIdx.x & 7, q = blockIdx.x >> 3;
  const int bm = (xcd >> 1) * nbm4 + q / nbn2;
  const int bn = (xcd & 1) * nbn2 + q % nbn2;
  const int row0 = bm << 7, col0 = bn << 7;
  const int NKT = K >> 6;

  f32x4 acc[4][4];
#pragma unroll
  for (int i = 0; i < 4; ++i)
#pragma unroll
    for (int j = 0; j < 4; ++j) acc[i][j] = (f32x4){0.f, 0.f, 0.f, 0.f};

  // Stage K-tile `tile` into buffer `buf` (0/1). 8 gload_lds16 per thread
  // (A 4, B 4; 32 rows per pass). Dest linear: row*128B + (l&7)*16B.
  // Source k pre-swizzled by ((row&7)<<4) bytes; row&7 == l>>3.
#define STAGE(tile, buf)                                                      \
  do {                                                                        \
    const int kt_ = (tile) << 6;                                              \
    const int kb_ = (((l & 7) ^ (l >> 3)) << 4) >> 1; /* shorts */            \
    const int rl_ = w * 8 + (l >> 3);                                         \
    _Pragma("unroll") for (int j_ = 0; j_ < 4; ++j_) {                        \
      gload_lds16(A + (size_t)(row0 + j_ * 32 + rl_) * K + kt_ + kb_,         \
                  lds + (buf) * 8192 + j_ * 2048 + w * 512);                  \
    }                                                                         \
    _Pragma("unroll") for (int j_ = 0; j_ < 4; ++j_) {                        \
      gload_lds16(Bm + (size_t)(col0 + j_ * 32 + rl_) * K + kt_ + kb_,        \
                  lds + 16384 + (buf) * 8192 + j_ * 2048 + w * 512);          \
    }                                                                         \
  } while (0)

  STAGE(0, 0);
  __syncthreads();

  const int ar = l & 15;
  const int swzk = (l & 7) << 4;               // bytes
  const int klo = (l >> 4) << 4;               // bytes
  const int kb0 = ((klo ^ swzk) >> 1);         // shorts, k-slice 0
  const int kb1 = (((klo + 64) ^ swzk) >> 1);  // shorts, k-slice 1

  for (int kt = 0; kt < NKT; ++kt) {
    const int cur = kt & 1;
    if (kt + 1 < NKT) STAGE(kt + 1, cur ^ 1);

    bf16x8 av[4][2], bv[4][2];
    const int abase = cur * 8192 + (wm * 64 + ar) * 64;
    const int bbase = 16384 + cur * 8192 + (wn * 64 + ar) * 64;
#pragma unroll
    for (int fm = 0; fm < 4; ++fm) {
      av[fm][0] = *(const bf16x8*)(lds + abase + fm * 1024 + kb0);
      av[fm][1] = *(const bf16x8*)(lds + abase + fm * 1024 + kb1);
    }
#pragma unroll
    for (int fn = 0; fn < 4; ++fn) {
      bv[fn][0] = *(const bf16x8*)(lds + bbase + fn * 1024 + kb0);
      bv[fn][1] = *(const bf16x8*)(lds + bbase + fn * 1024 + kb1);
    }
#pragma unroll
    for (int s = 0; s < 2; ++s)
#pragma unroll
      for (int fm = 0; fm < 4; ++fm)
#pragma unroll
        for (int fn = 0; fn < 4; ++fn)
          acc[fm][fn] = __builtin_amdgcn_mfma_f32_16x16x32_bf16(
              av[fm][s], bv[fn][s], acc[fm][fn], 0, 0, 0);
    __syncthreads();  // drains vmcnt+lgkmcnt: tile kt+1 landed, reads done
  }
#undef STAGE

  const float is = (MODE == 3) ? 1.0f : inv_sig[0];
#pragma unroll
  for (int fm = 0; fm < 4; ++fm) {
#pragma unroll
    for (int fn = 0; fn < 4; ++fn) {
      const int c = col0 + wn * 64 + fn * 16 + ar;
#pragma unroll
      for (int qq = 0; qq < 4; ++qq) {
        const int r = row0 + wm * 64 + fm * 16 + (l >> 4) * 4 + qq;
        const float v = acc[fm][fn][qq] * is;
        if (MODE == 0) {
          const float vv = v + bias[c] + bias2[c];
          outbf[(size_t)r * N + c] = f2bf(vv);
          outbf2[(size_t)r * N + c] = f2bf(tanhf(vv));
        } else if (MODE == 1) {
          outbf[(size_t)r * N + c] =
              f2bf(tanhf(v + bf2f(xpb[(size_t)r * N + c])));
        } else if (MODE == 2) {
          if (c < Nreal) outf[(size_t)r * Nreal + c] = v + bias[c];
        } else {
          outbf[(size_t)r * N + c] = f2bf(v);
        }
      }
    }
  }
}

// ---------------------------------------------------------------------------
// Fused f32 -> bf16 convert + transpose with row padding:
//   outN[Rpad][C] = bf16(in) (pad rows 0);  outT[C][Rpad] = bf16(in^T).
// ---------------------------------------------------------------------------
__global__ __launch_bounds__(256) void convT_b(const float* __restrict__ in,
                                               unsigned short* __restrict__ outN,
                                               unsigned short* __restrict__ outT,
                                               int Rpad, int C, int Rreal) {
  __shared__ float tile[32][33];
  const int c0 = blockIdx.x * 32, r0 = blockIdx.y * 32;
  const int tx = threadIdx.x & 31, ty = threadIdx.x >> 5;
  for (int i = ty; i < 32; i += 8) {
    const int r = r0 + i;
    const float v = (r < Rreal) ? in[(size_t)r * C + (c0 + tx)] : 0.f;
    outN[(size_t)r * C + (c0 + tx)] = f2bf(v);
    tile[i][tx] = v;
  }
  __syncthreads();
  for (int i = ty; i < 32; i += 8) {
    outT[(size_t)(c0 + i) * Rpad + (r0 + tx)] = f2bf(tile[tx][i]);
  }
}

// Row-dot helpers
__device__ __forceinline__ float dot_bf(const unsigned short* Mr,
                                        const float* xv, int dot, int l) {
  float s = 0.f;
#pragma unroll 4
  for (int j = l * 8; j < dot; j += 512) {
    const bf16x8 mv = *(const bf16x8*)(Mr + j);
    const float4 xa = *(const float4*)(xv + j);
    const float4 xb = *(const float4*)(xv + j + 4);
    s += bf2f((unsigned short)mv[0]) * xa.x + bf2f((unsigned short)mv[1]) * xa.y +
         bf2f((unsigned short)mv[2]) * xa.z + bf2f((unsigned short)mv[3]) * xa.w +
         bf2f((unsigned short)mv[4]) * xb.x + bf2f((unsigned short)mv[5]) * xb.y +
         bf2f((unsigned short)mv[6]) * xb.z + bf2f((unsigned short)mv[7]) * xb.w;
  }
  return s;
}
__device__ __forceinline__ float dot_f32(const float* Mr, const float* xv,
                                         int dot, int l) {
  float s = 0.f;
#pragma unroll 8
  for (int j = l * 4; j < dot; j += 256) {
    const float4 mv = *(const float4*)(Mr + j);
    const float4 xv4 = *(const float4*)(xv + j);
    s += mv.x * xv4.x + mv.y * xv4.y + mv.z * xv4.z + mv.w * xv4.w;
  }
  return s;
}
__device__ __forceinline__ float wave_red(float s) {
#pragma unroll
  for (int off = 32; off; off >>= 1) s += __shfl_down(s, off, 64);
  return s;
}

// fp32 matvec (sigma pass, exact weights): y[r] = mulv[r] * (row_r(M) . x)
struct MatDesc {
  const float* M;
  const float* x;
  float* y;
  const float* mulv;
  int rows, ld, dot, rreal;
};

__global__ __launch_bounds__(256) void matvec3(MatDesc d0, MatDesc d1,
                                               MatDesc d2, int n0, int n1) {
  int b = blockIdx.x;
  MatDesc d;
  if (b < n0) d = d0;
  else if (b < n0 + n1) { d = d1; b -= n0; }
  else { d = d2; b -= n0 + n1; }
  const int w = threadIdx.x >> 6, l = threadIdx.x & 63;
  const int r = b * 4 + w;
  if (r >= d.rows) return;
  float s = (r < d.rreal) ? dot_f32(d.M + (size_t)r * d.ld, d.x, d.dot, l) : 0.f;
  s = wave_red(s);
  if (l == 0) d.y[r] = (d.mulv ? d.mulv[r] : 1.f) * s;
}

// bf16 matvec (power-iteration passes): y[r] = row_r(M) . x
struct MatDescB {
  const unsigned short* M;
  const float* x;
  float* y;
  int rows, ld, dot;
};

__global__ __launch_bounds__(256) void matvec3b(MatDescB d0, MatDescB d1,
                                                MatDescB d2, int n0, int n1) {
  int b = blockIdx.x;
  MatDescB d;
  if (b < n0) d = d0;
  else if (b < n0 + n1) { d = d1; b -= n0; }
  else { d = d2; b -= n0 + n1; }
  const int w = threadIdx.x >> 6, l = threadIdx.x & 63;
  const int r = b * 4 + w;
  if (r >= d.rows) return;
  float s = dot_bf(d.M + (size_t)r * d.ld, d.x, d.dot, l);
  s = wave_red(s);
  if (l == 0) d.y[r] = s;
}

__global__ void init_p(float* p) {
  const int i = blockIdx.x * 256 + threadIdx.x;
  if (i < 5120) p[i] = (i < 5096) ? 1.f : 0.f;  // p_out rows 1000..1023 = 0
}

// Single-block deterministic reductions -> inv_sigma[3]
__global__ __launch_bounds__(256) void finalize_sigma(
    const float* __restrict__ p, const float* __restrict__ t,
    const float* __restrict__ cb, float* __restrict__ scal) {
  __shared__ float red[256];
  __shared__ float sres[9];
  const int segs[9][2] = {{0, 2048},    {2048, 2048}, {4096, 1024},
                          {0, 1024},    {1024, 2048}, {3072, 2048},
                          {0, 2048},    {2048, 2048}, {4096, 1024}};
  const float* bases[3] = {p, t, cb};
  for (int s = 0; s < 9; ++s) {
    const float* src = bases[s / 3] + segs[s][0];
    const int len = segs[s][1];
    float acc = 0.f;
    for (int i = threadIdx.x; i < len; i += 256) {
      const float v = src[i];
      acc += (s < 6) ? v * v : v;
    }
    red[threadIdx.x] = acc;
    __syncthreads();
    for (int st = 128; st; st >>= 1) {
      if (threadIdx.x < st) red[threadIdx.x] += red[threadIdx.x + st];
      __syncthreads();
    }
    if (threadIdx.x == 0) sres[s] = red[0];
    __syncthreads();
  }
  if (threadIdx.x == 0) {
    const float eps = 1e-12f;
    for (int m = 0; m < 3; ++m) {
      const float np = sqrtf(sres[m]);
      const float nt = sqrtf(sres[3 + m]);
      const float sig = sres[6 + m] / ((np + eps) * (nt + eps));
      scal[m] = 1.0f / sig;
    }
  }
}

// fp32 -> bf16 (x only)
__global__ __launch_bounds__(256) void f32_to_bf16_pad(
    const float* __restrict__ src, unsigned short* __restrict__ dst,
    long realTotal, long total) {
  const long idx = ((long)blockIdx.x * 256 + threadIdx.x) * 4;
  if (idx >= total) return;
  ushort4 o;
  if (idx < realTotal) {
    const float4 v = *(const float4*)(src + idx);
    o.x = f2bf(v.x); o.y = f2bf(v.y); o.z = f2bf(v.z); o.w = f2bf(v.w);
  } else {
    o.x = o.y = o.z = o.w = 0;
  }
  *(ushort4*)(dst + idx) = o;
}

// ---------------------------------------------------------------------------
extern "C" void kernel_launch(void* const* d_in, const int* in_sizes, int n_in,
                              void* d_out, int out_size, void* d_ws,
                              size_t ws_size, hipStream_t stream) {
  const float* x = (const float*)d_in[0];
  const float* W_in = (const float*)d_in[1];
  const float* b_in = (const float*)d_in[2];
  const float* W_rec = (const float*)d_in[3];
  const float* b_rec = (const float*)d_in[4];
  const float* W_out = (const float*)d_in[5];
  const float* b_out = (const float*)d_in[6];
  (void)in_sizes; (void)n_in; (void)out_size; (void)ws_size;

  const int B = 4096, DI = 1024, H = 2048, DO = 1000, DOP = 1024;
  const long MB = 1l << 20;

  char* ws = (char*)d_ws;
  unsigned short* Win_bf = (unsigned short*)(ws + 0 * MB);    // [2048][1024] 4MB
  unsigned short* Wrec_bf = (unsigned short*)(ws + 4 * MB);   // [2048][2048] 8MB
  unsigned short* Wout_bf = (unsigned short*)(ws + 12 * MB);  // [1024][2048] 4MB
  unsigned short* x_bf = (unsigned short*)(ws + 16 * MB);     // [4096][1024] 8MB
  unsigned short* xpb = (unsigned short*)(ws + 24 * MB);      // [4096][2048] 16MB
  // WT region (40..56MB) dead after the final W^T pass; h_a aliases it.
  unsigned short* WT_in_bf = (unsigned short*)(ws + 40 * MB);   // 4MB
  unsigned short* WT_rec_bf = (unsigned short*)(ws + 44 * MB);  // 8MB
  unsigned short* WT_out_bf = (unsigned short*)(ws + 52 * MB);  // 4MB
  unsigned short* h_a = (unsigned short*)(ws + 40 * MB);      // 16MB (alias WT)
  // H region (56..74MB) dead after the 30 H-passes; h_b aliases 56..72MB.
  unsigned short* H_in = (unsigned short*)(ws + 56 * MB);     // [2048][2048] 8MB
  unsigned short* H_rec = (unsigned short*)(ws + 64 * MB);    // [2048][2048] 8MB
  unsigned short* H_out = (unsigned short*)(ws + 72 * MB);    // [1024][1024] 2MB
  unsigned short* h_b = (unsigned short*)(ws + 56 * MB);      // 16MB (alias H)
  float* pvec = (float*)(ws + 76 * MB);
  float* tvec = pvec + 5120;
  float* cbuf = tvec + 5120;
  float* scal = cbuf + 5120;
  float* qvec = scal + 16;

  float* p_in = pvec, *p_rec = pvec + 2048, *p_out = pvec + 4096;
  float* t_in = tvec, *t_rec = tvec + 1024, *t_out = tvec + 3072;
  float* q_in = qvec, *q_rec = qvec + 2048, *q_out = qvec + 4096;

  // 1. Fused convert+transpose for weights; x convert.
  convT_b<<<dim3(DI / 32, H / 32), 256, 0, stream>>>(W_in, Win_bf, WT_in_bf,
                                                     H, DI, H);
  convT_b<<<dim3(H / 32, H / 32), 256, 0, stream>>>(W_rec, Wrec_bf, WT_rec_bf,
                                                    H, H, H);
  convT_b<<<dim3(H / 32, DOP / 32), 256, 0, stream>>>(W_out, Wout_bf,
                                                      WT_out_bf, DOP, H, DO);
  f32_to_bf16_pad<<<4096, 256, 0, stream>>>(x, x_bf, (long)B * DI, (long)B * DI);

  // 2a. H = bf16(W @ W^T) per matrix (MFMA GEMM, MODE 3).
  init_p<<<20, 256, 0, stream>>>(pvec);
  gemm3b<3><<<16 * 16, 256, 0, stream>>>(Win_bf, Win_bf, H, DI, 16, 16,
                                         nullptr, nullptr, nullptr, nullptr,
                                         nullptr, H_in, nullptr, H);
  gemm3b<3><<<16 * 16, 256, 0, stream>>>(Wrec_bf, Wrec_bf, H, H, 16, 16,
                                         nullptr, nullptr, nullptr, nullptr,
                                         nullptr, H_rec, nullptr, H);
  gemm3b<3><<<8 * 8, 256, 0, stream>>>(Wout_bf, Wout_bf, DOP, H, 8, 8,
                                       nullptr, nullptr, nullptr, nullptr,
                                       nullptr, H_out, nullptr, DOP);

  // 2b. 30 passes of u <- H u (ping-pong p <-> q), one fused launch each.
  MatDescB HpA = {H_in, p_in, q_in, 2048, 2048, 2048};
  MatDescB HpB = {H_rec, p_rec, q_rec, 2048, 2048, 2048};
  MatDescB HpC = {H_out, p_out, q_out, 1024, 1024, 1024};
  MatDescB HqA = {H_in, q_in, p_in, 2048, 2048, 2048};
  MatDescB HqB = {H_rec, q_rec, p_rec, 2048, 2048, 2048};
  MatDescB HqC = {H_out, q_out, p_out, 1024, 1024, 1024};
  for (int it = 0; it < NSTEPS / 2; ++it) {
    matvec3b<<<1280, 256, 0, stream>>>(HpA, HpB, HpC, 512, 512);
    matvec3b<<<1280, 256, 0, stream>>>(HqA, HqB, HqC, 512, 512);
  }
  // final: t = W^T u  (v unnormalized)
  MatDescB B1a = {WT_in_bf, p_in, t_in, 1024, 2048, 2048};
  MatDescB B1b = {WT_rec_bf, p_rec, t_rec, 2048, 2048, 2048};
  MatDescB B1c = {WT_out_bf, p_out, t_out, 2048, 1024, 1024};
  matvec3b<<<1280, 256, 0, stream>>>(B1a, B1b, B1c, 256, 512);

  // 3. sigma via exact fp32 W: c_i = p_i * (row_i(W) . t); then 1/sigma
  MatDesc sa = {W_in, t_in, cbuf, p_in, 2048, 1024, 1024, 2048};
  MatDesc sb = {W_rec, t_rec, cbuf + 2048, p_rec, 2048, 2048, 2048, 2048};
  MatDesc sc = {W_out, t_out, cbuf + 4096, p_out, 1024, 2048, 2048, 1000};
  matvec3<<<1280, 256, 0, stream>>>(sa, sb, sc, 512, 512);
  finalize_sigma<<<1, 256, 0, stream>>>(pvec, tvec, cbuf, scal);

  // 4. xpb = bf16(x @ Win^T * is0 + b_in + b_rec); h1 = tanh(same), fused
  gemm3b<0><<<32 * 16, 256, 0, stream>>>(
      x_bf, Win_bf, H, DI, 32, 16, b_in, b_rec, nullptr, scal + 0, nullptr,
      xpb, h_a, H);

  // 5. 29 recurrent GEMM steps ping-pong
  const unsigned short* hin = h_a;
  unsigned short* hout = h_b;
  for (int s = 2; s <= NSTEPS; ++s) {
    gemm3b<1><<<32 * 16, 256, 0, stream>>>(
        hin, Wrec_bf, H, H, 32, 16, nullptr, nullptr, xpb, scal + 1, nullptr,
        hout, nullptr, H);
    const unsigned short* tmp = hin;
    hin = hout;
    hout = (unsigned short*)tmp;
  }

  // 6. out = h @ Wout^T * is2 + b_out  (N padded to 1024, stores guarded)
  gemm3b<2><<<32 * 8, 256, 0, stream>>>(
      hin, Wout_bf, DOP, H, 32, 8, b_out, nullptr, nullptr, scal + 2,
      (float*)d_out, nullptr, nullptr, DO);
}

// Round 10
// 1353.714 us; speedup vs baseline: 1.8046x; 1.2445x over previous
//
#include <hip/hip_runtime.h>
#include <cstdint>
#include <cstddef>

#define NSTEPS 30

typedef __attribute__((ext_vector_type(4))) float f32x4;
typedef __attribute__((ext_vector_type(8))) short bf16x8;

__device__ __forceinline__ unsigned short f2bf(float f) {
  union { float f; unsigned int u; } v; v.f = f;
  return (unsigned short)((v.u + 0x7FFFu + ((v.u >> 16) & 1u)) >> 16);
}
__device__ __forceinline__ float bf2f(unsigned short u) {
  union { unsigned int u; float f; } v; v.u = ((unsigned int)u) << 16;
  return v.f;
}
// fast tanh: exact at saturation (exp->inf => 1; exp->0 => -1), ~1e-7 err
__device__ __forceinline__ float ftanh(float x) {
  return 1.0f - 2.0f / (__expf(2.0f * x) + 1.0f);
}

__device__ __forceinline__ void gload_lds16(const void* g, void* l) {
  __builtin_amdgcn_global_load_lds(
      (const __attribute__((address_space(1))) unsigned int*)g,
      (__attribute__((address_space(3))) unsigned int*)l, 16, 0, 0);
}

// ---------------------------------------------------------------------------
// 128x128-tile GEMM, BK=64, double-buffered 2-phase, 2 blocks/CU: C = A @ B^T.
// 4 waves (2M x 2N), per-wave 64x64 = 4x4 frags of mfma 16x16x32 bf16.
// LDS 64 KiB: A dbuf [128][64] + B dbuf [128][64], XOR-swizzled.
// MODE 0: xpb = bf16(acc*is + bias + bias2); outbf2 = bf16(tanh(same))
// MODE 1: outbf = bf16(tanh(acc*is + xpb))
// MODE 2: if c<Nreal: outf[r*Nreal+c] = acc*is + bias[c]
// MODE 3: outbf = bf16(acc)            (H = W @ W^T / G = H @ H^T builds)
// ---------------------------------------------------------------------------
template <int MODE>
__global__ __launch_bounds__(256, 2) void gemm3b(
    const unsigned short* __restrict__ A, const unsigned short* __restrict__ Bm,
    int N, int K, int nbm, int nbn, const float* __restrict__ bias,
    const float* __restrict__ bias2, const unsigned short* __restrict__ xpb,
    const float* __restrict__ inv_sig, float* __restrict__ outf,
    unsigned short* __restrict__ outbf, unsigned short* __restrict__ outbf2,
    int Nreal) {
  __shared__ short lds[32768];  // 64 KiB: A 2x8192, B 2x8192 (shorts)
  const int t = threadIdx.x, w = t >> 6, l = t & 63;
  const int wm = w >> 1, wn = w & 1;  // 2M x 2N wave grid
  const int nbn2 = nbn >> 1, nbm4 = nbm >> 2;
  const int xcd = blockIdx.x & 7, q = blockIdx.x >> 3;
  const int bm = (xcd >> 1) * nbm4 + q / nbn2;
  const int bn = (xcd & 1) * nbn2 + q % nbn2;
  const int row0 = bm << 7, col0 = bn << 7;
  const int NKT = K >> 6;

  f32x4 acc[4][4];
#pragma unroll
  for (int i = 0; i < 4; ++i)
#pragma unroll
    for (int j = 0; j < 4; ++j) acc[i][j] = (f32x4){0.f, 0.f, 0.f, 0.f};

#define STAGE(tile, buf)                                                      \
  do {                                                                        \
    const int kt_ = (tile) << 6;                                              \
    const int kb_ = (((l & 7) ^ (l >> 3)) << 4) >> 1; /* shorts */            \
    const int rl_ = w * 8 + (l >> 3);                                         \
    _Pragma("unroll") for (int j_ = 0; j_ < 4; ++j_) {                        \
      gload_lds16(A + (size_t)(row0 + j_ * 32 + rl_) * K + kt_ + kb_,         \
                  lds + (buf) * 8192 + j_ * 2048 + w * 512);                  \
    }                                                                         \
    _Pragma("unroll") for (int j_ = 0; j_ < 4; ++j_) {                        \
      gload_lds16(Bm + (size_t)(col0 + j_ * 32 + rl_) * K + kt_ + kb_,        \
                  lds + 16384 + (buf) * 8192 + j_ * 2048 + w * 512);          \
    }                                                                         \
  } while (0)

  STAGE(0, 0);
  __syncthreads();

  const int ar = l & 15;
  const int swzk = (l & 7) << 4;               // bytes
  const int klo = (l >> 4) << 4;               // bytes
  const int kb0 = ((klo ^ swzk) >> 1);         // shorts, k-slice 0
  const int kb1 = (((klo + 64) ^ swzk) >> 1);  // shorts, k-slice 1

  for (int kt = 0; kt < NKT; ++kt) {
    const int cur = kt & 1;
    if (kt + 1 < NKT) STAGE(kt + 1, cur ^ 1);

    bf16x8 av[4][2], bv[4][2];
    const int abase = cur * 8192 + (wm * 64 + ar) * 64;
    const int bbase = 16384 + cur * 8192 + (wn * 64 + ar) * 64;
#pragma unroll
    for (int fm = 0; fm < 4; ++fm) {
      av[fm][0] = *(const bf16x8*)(lds + abase + fm * 1024 + kb0);
      av[fm][1] = *(const bf16x8*)(lds + abase + fm * 1024 + kb1);
    }
#pragma unroll
    for (int fn = 0; fn < 4; ++fn) {
      bv[fn][0] = *(const bf16x8*)(lds + bbase + fn * 1024 + kb0);
      bv[fn][1] = *(const bf16x8*)(lds + bbase + fn * 1024 + kb1);
    }
#pragma unroll
    for (int s = 0; s < 2; ++s)
#pragma unroll
      for (int fm = 0; fm < 4; ++fm)
#pragma unroll
        for (int fn = 0; fn < 4; ++fn)
          acc[fm][fn] = __builtin_amdgcn_mfma_f32_16x16x32_bf16(
              av[fm][s], bv[fn][s], acc[fm][fn], 0, 0, 0);
    __syncthreads();  // drains vmcnt+lgkmcnt: tile kt+1 landed, reads done
  }
#undef STAGE

  const float is = (MODE == 3) ? 1.0f : inv_sig[0];
#pragma unroll
  for (int fm = 0; fm < 4; ++fm) {
#pragma unroll
    for (int fn = 0; fn < 4; ++fn) {
      const int c = col0 + wn * 64 + fn * 16 + ar;
#pragma unroll
      for (int qq = 0; qq < 4; ++qq) {
        const int r = row0 + wm * 64 + fm * 16 + (l >> 4) * 4 + qq;
        const float v = acc[fm][fn][qq] * is;
        if (MODE == 0) {
          const float vv = v + bias[c] + bias2[c];
          outbf[(size_t)r * N + c] = f2bf(vv);
          outbf2[(size_t)r * N + c] = f2bf(ftanh(vv));
        } else if (MODE == 1) {
          outbf[(size_t)r * N + c] =
              f2bf(ftanh(v + bf2f(xpb[(size_t)r * N + c])));
        } else if (MODE == 2) {
          if (c < Nreal) outf[(size_t)r * Nreal + c] = v + bias[c];
        } else {
          outbf[(size_t)r * N + c] = f2bf(v);
        }
      }
    }
  }
}

// ---------------------------------------------------------------------------
// Fused f32 -> bf16 convert + transpose with row padding:
//   outN[Rpad][C] = bf16(in) (pad rows 0);  outT[C][Rpad] = bf16(in^T).
// ---------------------------------------------------------------------------
__global__ __launch_bounds__(256) void convT_b(const float* __restrict__ in,
                                               unsigned short* __restrict__ outN,
                                               unsigned short* __restrict__ outT,
                                               int Rpad, int C, int Rreal) {
  __shared__ float tile[32][33];
  const int c0 = blockIdx.x * 32, r0 = blockIdx.y * 32;
  const int tx = threadIdx.x & 31, ty = threadIdx.x >> 5;
  for (int i = ty; i < 32; i += 8) {
    const int r = r0 + i;
    const float v = (r < Rreal) ? in[(size_t)r * C + (c0 + tx)] : 0.f;
    outN[(size_t)r * C + (c0 + tx)] = f2bf(v);
    tile[i][tx] = v;
  }
  __syncthreads();
  for (int i = ty; i < 32; i += 8) {
    outT[(size_t)(c0 + i) * Rpad + (r0 + tx)] = f2bf(tile[tx][i]);
  }
}

// Row-dot helpers
__device__ __forceinline__ float dot_bf(const unsigned short* Mr,
                                        const float* xv, int dot, int l) {
  float s = 0.f;
#pragma unroll 4
  for (int j = l * 8; j < dot; j += 512) {
    const bf16x8 mv = *(const bf16x8*)(Mr + j);
    const float4 xa = *(const float4*)(xv + j);
    const float4 xb = *(const float4*)(xv + j + 4);
    s += bf2f((unsigned short)mv[0]) * xa.x + bf2f((unsigned short)mv[1]) * xa.y +
         bf2f((unsigned short)mv[2]) * xa.z + bf2f((unsigned short)mv[3]) * xa.w +
         bf2f((unsigned short)mv[4]) * xb.x + bf2f((unsigned short)mv[5]) * xb.y +
         bf2f((unsigned short)mv[6]) * xb.z + bf2f((unsigned short)mv[7]) * xb.w;
  }
  return s;
}
__device__ __forceinline__ float dot_f32(const float* Mr, const float* xv,
                                         int dot, int l) {
  float s = 0.f;
#pragma unroll 8
  for (int j = l * 4; j < dot; j += 256) {
    const float4 mv = *(const float4*)(Mr + j);
    const float4 xv4 = *(const float4*)(xv + j);
    s += mv.x * xv4.x + mv.y * xv4.y + mv.z * xv4.z + mv.w * xv4.w;
  }
  return s;
}
__device__ __forceinline__ float wave_red(float s) {
#pragma unroll
  for (int off = 32; off; off >>= 1) s += __shfl_down(s, off, 64);
  return s;
}

// fp32 matvec (sigma pass, exact weights): y[r] = mulv[r] * (row_r(M) . x)
struct MatDesc {
  const float* M;
  const float* x;
  float* y;
  const float* mulv;
  int rows, ld, dot, rreal;
};

__global__ __launch_bounds__(256) void matvec3(MatDesc d0, MatDesc d1,
                                               MatDesc d2, int n0, int n1) {
  int b = blockIdx.x;
  MatDesc d;
  if (b < n0) d = d0;
  else if (b < n0 + n1) { d = d1; b -= n0; }
  else { d = d2; b -= n0 + n1; }
  const int w = threadIdx.x >> 6, l = threadIdx.x & 63;
  const int r = b * 4 + w;
  if (r >= d.rows) return;
  float s = (r < d.rreal) ? dot_f32(d.M + (size_t)r * d.ld, d.x, d.dot, l) : 0.f;
  s = wave_red(s);
  if (l == 0) d.y[r] = (d.mulv ? d.mulv[r] : 1.f) * s;
}

// bf16 matvec (power-iteration passes): y[r] = row_r(M) . x
struct MatDescB {
  const unsigned short* M;
  const float* x;
  float* y;
  int rows, ld, dot;
};

__global__ __launch_bounds__(256) void matvec3b(MatDescB d0, MatDescB d1,
                                                MatDescB d2, int n0, int n1) {
  int b = blockIdx.x;
  MatDescB d;
  if (b < n0) d = d0;
  else if (b < n0 + n1) { d = d1; b -= n0; }
  else { d = d2; b -= n0 + n1; }
  const int w = threadIdx.x >> 6, l = threadIdx.x & 63;
  const int r = b * 4 + w;
  if (r >= d.rows) return;
  float s = dot_bf(d.M + (size_t)r * d.ld, d.x, d.dot, l);
  s = wave_red(s);
  if (l == 0) d.y[r] = s;
}

__global__ void init_p(float* p) {
  const int i = blockIdx.x * 256 + threadIdx.x;
  if (i < 5120) p[i] = (i < 5096) ? 1.f : 0.f;  // p_out rows 1000..1023 = 0
}

// Single-block deterministic reductions -> inv_sigma[3]
__global__ __launch_bounds__(256) void finalize_sigma(
    const float* __restrict__ p, const float* __restrict__ t,
    const float* __restrict__ cb, float* __restrict__ scal) {
  __shared__ float red[256];
  __shared__ float sres[9];
  const int segs[9][2] = {{0, 2048},    {2048, 2048}, {4096, 1024},
                          {0, 1024},    {1024, 2048}, {3072, 2048},
                          {0, 2048},    {2048, 2048}, {4096, 1024}};
  const float* bases[3] = {p, t, cb};
  for (int s = 0; s < 9; ++s) {
    const float* src = bases[s / 3] + segs[s][0];
    const int len = segs[s][1];
    float acc = 0.f;
    for (int i = threadIdx.x; i < len; i += 256) {
      const float v = src[i];
      acc += (s < 6) ? v * v : v;
    }
    red[threadIdx.x] = acc;
    __syncthreads();
    for (int st = 128; st; st >>= 1) {
      if (threadIdx.x < st) red[threadIdx.x] += red[threadIdx.x + st];
      __syncthreads();
    }
    if (threadIdx.x == 0) sres[s] = red[0];
    __syncthreads();
  }
  if (threadIdx.x == 0) {
    const float eps = 1e-12f;
    for (int m = 0; m < 3; ++m) {
      const float np = sqrtf(sres[m]);
      const float nt = sqrtf(sres[3 + m]);
      const float sig = sres[6 + m] / ((np + eps) * (nt + eps));
      scal[m] = 1.0f / sig;
    }
  }
}

// fp32 -> bf16 (x only)
__global__ __launch_bounds__(256) void f32_to_bf16_pad(
    const float* __restrict__ src, unsigned short* __restrict__ dst,
    long realTotal, long total) {
  const long idx = ((long)blockIdx.x * 256 + threadIdx.x) * 4;
  if (idx >= total) return;
  ushort4 o;
  if (idx < realTotal) {
    const float4 v = *(const float4*)(src + idx);
    o.x = f2bf(v.x); o.y = f2bf(v.y); o.z = f2bf(v.z); o.w = f2bf(v.w);
  } else {
    o.x = o.y = o.z = o.w = 0;
  }
  *(ushort4*)(dst + idx) = o;
}

// ---------------------------------------------------------------------------
extern "C" void kernel_launch(void* const* d_in, const int* in_sizes, int n_in,
                              void* d_out, int out_size, void* d_ws,
                              size_t ws_size, hipStream_t stream) {
  const float* x = (const float*)d_in[0];
  const float* W_in = (const float*)d_in[1];
  const float* b_in = (const float*)d_in[2];
  const float* W_rec = (const float*)d_in[3];
  const float* b_rec = (const float*)d_in[4];
  const float* W_out = (const float*)d_in[5];
  const float* b_out = (const float*)d_in[6];
  (void)in_sizes; (void)n_in; (void)out_size; (void)ws_size;

  const int B = 4096, DI = 1024, H = 2048, DO = 1000, DOP = 1024;
  const long MB = 1l << 20;

  char* ws = (char*)d_ws;
  unsigned short* Win_bf = (unsigned short*)(ws + 0 * MB);    // [2048][1024] 4MB
  unsigned short* Wrec_bf = (unsigned short*)(ws + 4 * MB);   // [2048][2048] 8MB
  unsigned short* Wout_bf = (unsigned short*)(ws + 12 * MB);  // [1024][2048] 4MB
  unsigned short* x_bf = (unsigned short*)(ws + 16 * MB);     // [4096][1024] 8MB
  // G region (24..40MB) dead after power; xpb aliases it (written at MODE0).
  unsigned short* G_in = (unsigned short*)(ws + 24 * MB);     // [2048][2048] 8MB
  unsigned short* G_rec = (unsigned short*)(ws + 32 * MB);    // [2048][2048] 8MB
  unsigned short* xpb = (unsigned short*)(ws + 24 * MB);      // [4096][2048] 16MB
  // WT region (40..56MB) dead after the final W^T pass; h_a aliases it.
  unsigned short* WT_in_bf = (unsigned short*)(ws + 40 * MB);   // 4MB
  unsigned short* WT_rec_bf = (unsigned short*)(ws + 44 * MB);  // 8MB
  unsigned short* WT_out_bf = (unsigned short*)(ws + 52 * MB);  // 4MB
  unsigned short* h_a = (unsigned short*)(ws + 40 * MB);      // 16MB (alias WT)
  // H region (56..74MB) dead after G-build; h_b aliases 56..72MB.
  unsigned short* H_in = (unsigned short*)(ws + 56 * MB);     // [2048][2048] 8MB
  unsigned short* H_rec = (unsigned short*)(ws + 64 * MB);    // [2048][2048] 8MB
  unsigned short* H_out = (unsigned short*)(ws + 72 * MB);    // [1024][1024] 2MB
  unsigned short* h_b = (unsigned short*)(ws + 56 * MB);      // 16MB (alias H)
  unsigned short* G_out = (unsigned short*)(ws + 74 * MB);    // [1024][1024] 2MB
  float* pvec = (float*)(ws + 76 * MB);
  float* tvec = pvec + 5120;
  float* cbuf = tvec + 5120;
  float* scal = cbuf + 5120;
  float* qvec = scal + 16;

  float* p_in = pvec, *p_rec = pvec + 2048, *p_out = pvec + 4096;
  float* t_in = tvec, *t_rec = tvec + 1024, *t_out = tvec + 3072;
  float* q_in = qvec, *q_rec = qvec + 2048, *q_out = qvec + 4096;

  // 1. Fused convert+transpose for weights; x convert.
  convT_b<<<dim3(DI / 32, H / 32), 256, 0, stream>>>(W_in, Win_bf, WT_in_bf,
                                                     H, DI, H);
  convT_b<<<dim3(H / 32, H / 32), 256, 0, stream>>>(W_rec, Wrec_bf, WT_rec_bf,
                                                    H, H, H);
  convT_b<<<dim3(H / 32, DOP / 32), 256, 0, stream>>>(W_out, Wout_bf,
                                                      WT_out_bf, DOP, H, DO);
  f32_to_bf16_pad<<<4096, 256, 0, stream>>>(x, x_bf, (long)B * DI, (long)B * DI);

  // 2a. H = bf16(W @ W^T); then G = bf16(H @ H^T) = H^2 (H symmetric).
  init_p<<<20, 256, 0, stream>>>(pvec);
  gemm3b<3><<<16 * 16, 256, 0, stream>>>(Win_bf, Win_bf, H, DI, 16, 16,
                                         nullptr, nullptr, nullptr, nullptr,
                                         nullptr, H_in, nullptr, H);
  gemm3b<3><<<16 * 16, 256, 0, stream>>>(Wrec_bf, Wrec_bf, H, H, 16, 16,
                                         nullptr, nullptr, nullptr, nullptr,
                                         nullptr, H_rec, nullptr, H);
  gemm3b<3><<<8 * 8, 256, 0, stream>>>(Wout_bf, Wout_bf, DOP, H, 8, 8,
                                       nullptr, nullptr, nullptr, nullptr,
                                       nullptr, H_out, nullptr, DOP);
  gemm3b<3><<<16 * 16, 256, 0, stream>>>(H_in, H_in, H, H, 16, 16, nullptr,
                                         nullptr, nullptr, nullptr, nullptr,
                                         G_in, nullptr, H);
  gemm3b<3><<<16 * 16, 256, 0, stream>>>(H_rec, H_rec, H, H, 16, 16, nullptr,
                                         nullptr, nullptr, nullptr, nullptr,
                                         G_rec, nullptr, H);
  gemm3b<3><<<8 * 8, 256, 0, stream>>>(H_out, H_out, DOP, DOP, 8, 8, nullptr,
                                       nullptr, nullptr, nullptr, nullptr,
                                       G_out, nullptr, DOP);

  // 2b. 15 passes of u <- G u  (= H^30 u). Ends with u in qvec.
  MatDescB GpA = {G_in, p_in, q_in, 2048, 2048, 2048};
  MatDescB GpB = {G_rec, p_rec, q_rec, 2048, 2048, 2048};
  MatDescB GpC = {G_out, p_out, q_out, 1024, 1024, 1024};
  MatDescB GqA = {G_in, q_in, p_in, 2048, 2048, 2048};
  MatDescB GqB = {G_rec, q_rec, p_rec, 2048, 2048, 2048};
  MatDescB GqC = {G_out, q_out, p_out, 1024, 1024, 1024};
  for (int it = 0; it < 7; ++it) {
    matvec3b<<<1280, 256, 0, stream>>>(GpA, GpB, GpC, 512, 512);
    matvec3b<<<1280, 256, 0, stream>>>(GqA, GqB, GqC, 512, 512);
  }
  matvec3b<<<1280, 256, 0, stream>>>(GpA, GpB, GpC, 512, 512);  // pass 15 -> q
  // final: t = W^T u  (v unnormalized)
  MatDescB B1a = {WT_in_bf, q_in, t_in, 1024, 2048, 2048};
  MatDescB B1b = {WT_rec_bf, q_rec, t_rec, 2048, 2048, 2048};
  MatDescB B1c = {WT_out_bf, q_out, t_out, 2048, 1024, 1024};
  matvec3b<<<1280, 256, 0, stream>>>(B1a, B1b, B1c, 256, 512);

  // 3. sigma via exact fp32 W: c_i = u_i * (row_i(W) . t); then 1/sigma
  MatDesc sa = {W_in, t_in, cbuf, q_in, 2048, 1024, 1024, 2048};
  MatDesc sb = {W_rec, t_rec, cbuf + 2048, q_rec, 2048, 2048, 2048, 2048};
  MatDesc sc = {W_out, t_out, cbuf + 4096, q_out, 1024, 2048, 2048, 1000};
  matvec3<<<1280, 256, 0, stream>>>(sa, sb, sc, 512, 512);
  finalize_sigma<<<1, 256, 0, stream>>>(qvec, tvec, cbuf, scal);

  // 4. xpb = bf16(x @ Win^T * is0 + b_in + b_rec); h1 = tanh(same), fused
  gemm3b<0><<<32 * 16, 256, 0, stream>>>(
      x_bf, Win_bf, H, DI, 32, 16, b_in, b_rec, nullptr, scal + 0, nullptr,
      xpb, h_a, H);

  // 5. 29 recurrent GEMM steps ping-pong
  const unsigned short* hin = h_a;
  unsigned short* hout = h_b;
  for (int s = 2; s <= NSTEPS; ++s) {
    gemm3b<1><<<32 * 16, 256, 0, stream>>>(
        hin, Wrec_bf, H, H, 32, 16, nullptr, nullptr, xpb, scal + 1, nullptr,
        hout, nullptr, H);
    const unsigned short* tmp = hin;
    hin = hout;
    hout = (unsigned short*)tmp;
  }

  // 6. out = h @ Wout^T * is2 + b_out  (N padded to 1024, stores guarded)
  gemm3b<2><<<32 * 8, 256, 0, stream>>>(
      hin, Wout_bf, DOP, H, 32, 8, b_out, nullptr, nullptr, scal + 2,
      (float*)d_out, nullptr, nullptr, DO);
}

// Round 11
// 1296.695 us; speedup vs baseline: 1.8840x; 1.0440x over previous
//
#include <hip/hip_runtime.h>
#include <cstdint>
#include <cstddef>

#define NSTEPS 30

typedef __attribute__((ext_vector_type(4))) float f32x4;
typedef __attribute__((ext_vector_type(8))) short bf16x8;

__device__ __forceinline__ unsigned short f2bf(float f) {
  union { float f; unsigned int u; } v; v.f = f;
  return (unsigned short)((v.u + 0x7FFFu + ((v.u >> 16) & 1u)) >> 16);
}
__device__ __forceinline__ float bf2f(unsigned short u) {
  union { unsigned int u; float f; } v; v.u = ((unsigned int)u) << 16;
  return v.f;
}
// fast tanh: exact at saturation (exp->inf => 1; exp->0 => -1), ~1e-7 err
__device__ __forceinline__ float ftanh(float x) {
  return 1.0f - 2.0f / (__expf(2.0f * x) + 1.0f);
}

__device__ __forceinline__ void gload_lds16(const void* g, void* l) {
  __builtin_amdgcn_global_load_lds(
      (const __attribute__((address_space(1))) unsigned int*)g,
      (__attribute__((address_space(3))) unsigned int*)l, 16, 0, 0);
}

// ---------------------------------------------------------------------------
// 128x128-tile GEMM, BK=64, double-buffered 2-phase, 2 blocks/CU: C = A @ B^T.
// 4 waves (2M x 2N), per-wave 64x64 = 4x4 frags of mfma 16x16x32 bf16.
// LDS 64 KiB: A dbuf [128][64] + B dbuf [128][64], XOR-swizzled.
// T5: setprio(1) around the MFMA cluster — with 2 independent blocks/CU at
// uncorrelated phases, the CU scheduler favors the block in its MFMA phase
// over the co-resident block's staging VALU (m191 mechanism).
// MODE 0: xpb = bf16(acc*is + bias + bias2); outbf2 = bf16(tanh(same))
// MODE 1: outbf = bf16(tanh(acc*is + xpb))
// MODE 2: if c<Nreal: outf[r*Nreal+c] = acc*is + bias[c]
// MODE 3: outbf = bf16(acc)            (H = W @ W^T / G = H @ H^T builds)
// ---------------------------------------------------------------------------
template <int MODE>
__global__ __launch_bounds__(256, 2) void gemm3b(
    const unsigned short* __restrict__ A, const unsigned short* __restrict__ Bm,
    int N, int K, int nbm, int nbn, const float* __restrict__ bias,
    const float* __restrict__ bias2, const unsigned short* __restrict__ xpb,
    const float* __restrict__ inv_sig, float* __restrict__ outf,
    unsigned short* __restrict__ outbf, unsigned short* __restrict__ outbf2,
    int Nreal) {
  __shared__ short lds[32768];  // 64 KiB: A 2x8192, B 2x8192 (shorts)
  const int t = threadIdx.x, w = t >> 6, l = t & 63;
  const int wm = w >> 1, wn = w & 1;  // 2M x 2N wave grid
  const int nbn2 = nbn >> 1, nbm4 = nbm >> 2;
  const int xcd = blockIdx.x & 7, q = blockIdx.x >> 3;
  const int bm = (xcd >> 1) * nbm4 + q / nbn2;
  const int bn = (xcd & 1) * nbn2 + q % nbn2;
  const int row0 = bm << 7, col0 = bn << 7;
  const int NKT = K >> 6;

  f32x4 acc[4][4];
#pragma unroll
  for (int i = 0; i < 4; ++i)
#pragma unroll
    for (int j = 0; j < 4; ++j) acc[i][j] = (f32x4){0.f, 0.f, 0.f, 0.f};

#define STAGE(tile, buf)                                                      \
  do {                                                                        \
    const int kt_ = (tile) << 6;                                              \
    const int kb_ = (((l & 7) ^ (l >> 3)) << 4) >> 1; /* shorts */            \
    const int rl_ = w * 8 + (l >> 3);                                         \
    _Pragma("unroll") for (int j_ = 0; j_ < 4; ++j_) {                        \
      gload_lds16(A + (size_t)(row0 + j_ * 32 + rl_) * K + kt_ + kb_,         \
                  lds + (buf) * 8192 + j_ * 2048 + w * 512);                  \
    }                                                                         \
    _Pragma("unroll") for (int j_ = 0; j_ < 4; ++j_) {                        \
      gload_lds16(Bm + (size_t)(col0 + j_ * 32 + rl_) * K + kt_ + kb_,        \
                  lds + 16384 + (buf) * 8192 + j_ * 2048 + w * 512);          \
    }                                                                         \
  } while (0)

  STAGE(0, 0);
  __syncthreads();

  const int ar = l & 15;
  const int swzk = (l & 7) << 4;               // bytes
  const int klo = (l >> 4) << 4;               // bytes
  const int kb0 = ((klo ^ swzk) >> 1);         // shorts, k-slice 0
  const int kb1 = (((klo + 64) ^ swzk) >> 1);  // shorts, k-slice 1

  for (int kt = 0; kt < NKT; ++kt) {
    const int cur = kt & 1;
    if (kt + 1 < NKT) STAGE(kt + 1, cur ^ 1);

    bf16x8 av[4][2], bv[4][2];
    const int abase = cur * 8192 + (wm * 64 + ar) * 64;
    const int bbase = 16384 + cur * 8192 + (wn * 64 + ar) * 64;
#pragma unroll
    for (int fm = 0; fm < 4; ++fm) {
      av[fm][0] = *(const bf16x8*)(lds + abase + fm * 1024 + kb0);
      av[fm][1] = *(const bf16x8*)(lds + abase + fm * 1024 + kb1);
    }
#pragma unroll
    for (int fn = 0; fn < 4; ++fn) {
      bv[fn][0] = *(const bf16x8*)(lds + bbase + fn * 1024 + kb0);
      bv[fn][1] = *(const bf16x8*)(lds + bbase + fn * 1024 + kb1);
    }
    __builtin_amdgcn_s_setprio(1);
#pragma unroll
    for (int s = 0; s < 2; ++s)
#pragma unroll
      for (int fm = 0; fm < 4; ++fm)
#pragma unroll
        for (int fn = 0; fn < 4; ++fn)
          acc[fm][fn] = __builtin_amdgcn_mfma_f32_16x16x32_bf16(
              av[fm][s], bv[fn][s], acc[fm][fn], 0, 0, 0);
    __builtin_amdgcn_s_setprio(0);
    __syncthreads();  // drains vmcnt+lgkmcnt: tile kt+1 landed, reads done
  }
#undef STAGE

  const float is = (MODE == 3) ? 1.0f : inv_sig[0];
#pragma unroll
  for (int fm = 0; fm < 4; ++fm) {
#pragma unroll
    for (int fn = 0; fn < 4; ++fn) {
      const int c = col0 + wn * 64 + fn * 16 + ar;
#pragma unroll
      for (int qq = 0; qq < 4; ++qq) {
        const int r = row0 + wm * 64 + fm * 16 + (l >> 4) * 4 + qq;
        const float v = acc[fm][fn][qq] * is;
        if (MODE == 0) {
          const float vv = v + bias[c] + bias2[c];
          outbf[(size_t)r * N + c] = f2bf(vv);
          outbf2[(size_t)r * N + c] = f2bf(ftanh(vv));
        } else if (MODE == 1) {
          outbf[(size_t)r * N + c] =
              f2bf(ftanh(v + bf2f(xpb[(size_t)r * N + c])));
        } else if (MODE == 2) {
          if (c < Nreal) outf[(size_t)r * Nreal + c] = v + bias[c];
        } else {
          outbf[(size_t)r * N + c] = f2bf(v);
        }
      }
    }
  }
}

// ---------------------------------------------------------------------------
// Fused f32 -> bf16 convert + transpose with row padding:
//   outN[Rpad][C] = bf16(in) (pad rows 0);  outT[C][Rpad] = bf16(in^T).
// ---------------------------------------------------------------------------
__global__ __launch_bounds__(256) void convT_b(const float* __restrict__ in,
                                               unsigned short* __restrict__ outN,
                                               unsigned short* __restrict__ outT,
                                               int Rpad, int C, int Rreal) {
  __shared__ float tile[32][33];
  const int c0 = blockIdx.x * 32, r0 = blockIdx.y * 32;
  const int tx = threadIdx.x & 31, ty = threadIdx.x >> 5;
  for (int i = ty; i < 32; i += 8) {
    const int r = r0 + i;
    const float v = (r < Rreal) ? in[(size_t)r * C + (c0 + tx)] : 0.f;
    outN[(size_t)r * C + (c0 + tx)] = f2bf(v);
    tile[i][tx] = v;
  }
  __syncthreads();
  for (int i = ty; i < 32; i += 8) {
    outT[(size_t)(c0 + i) * Rpad + (r0 + tx)] = f2bf(tile[tx][i]);
  }
}

// Row-dot helpers
__device__ __forceinline__ float dot_bf(const unsigned short* Mr,
                                        const float* xv, int dot, int l) {
  float s = 0.f;
#pragma unroll 4
  for (int j = l * 8; j < dot; j += 512) {
    const bf16x8 mv = *(const bf16x8*)(Mr + j);
    const float4 xa = *(const float4*)(xv + j);
    const float4 xb = *(const float4*)(xv + j + 4);
    s += bf2f((unsigned short)mv[0]) * xa.x + bf2f((unsigned short)mv[1]) * xa.y +
         bf2f((unsigned short)mv[2]) * xa.z + bf2f((unsigned short)mv[3]) * xa.w +
         bf2f((unsigned short)mv[4]) * xb.x + bf2f((unsigned short)mv[5]) * xb.y +
         bf2f((unsigned short)mv[6]) * xb.z + bf2f((unsigned short)mv[7]) * xb.w;
  }
  return s;
}
__device__ __forceinline__ float dot_f32(const float* Mr, const float* xv,
                                         int dot, int l) {
  float s = 0.f;
#pragma unroll 8
  for (int j = l * 4; j < dot; j += 256) {
    const float4 mv = *(const float4*)(Mr + j);
    const float4 xv4 = *(const float4*)(xv + j);
    s += mv.x * xv4.x + mv.y * xv4.y + mv.z * xv4.z + mv.w * xv4.w;
  }
  return s;
}
__device__ __forceinline__ float wave_red(float s) {
#pragma unroll
  for (int off = 32; off; off >>= 1) s += __shfl_down(s, off, 64);
  return s;
}

// fp32 matvec (sigma pass, exact weights): y[r] = mulv[r] * (row_r(M) . x)
struct MatDesc {
  const float* M;
  const float* x;
  float* y;
  const float* mulv;
  int rows, ld, dot, rreal;
};

__global__ __launch_bounds__(256) void matvec3(MatDesc d0, MatDesc d1,
                                               MatDesc d2, int n0, int n1) {
  int b = blockIdx.x;
  MatDesc d;
  if (b < n0) d = d0;
  else if (b < n0 + n1) { d = d1; b -= n0; }
  else { d = d2; b -= n0 + n1; }
  const int w = threadIdx.x >> 6, l = threadIdx.x & 63;
  const int r = b * 4 + w;
  if (r >= d.rows) return;
  float s = (r < d.rreal) ? dot_f32(d.M + (size_t)r * d.ld, d.x, d.dot, l) : 0.f;
  s = wave_red(s);
  if (l == 0) d.y[r] = (d.mulv ? d.mulv[r] : 1.f) * s;
}

// bf16 matvec (power-iteration passes): y[r] = row_r(M) . x
struct MatDescB {
  const unsigned short* M;
  const float* x;
  float* y;
  int rows, ld, dot;
};

__global__ __launch_bounds__(256) void matvec3b(MatDescB d0, MatDescB d1,
                                                MatDescB d2, int n0, int n1) {
  int b = blockIdx.x;
  MatDescB d;
  if (b < n0) d = d0;
  else if (b < n0 + n1) { d = d1; b -= n0; }
  else { d = d2; b -= n0 + n1; }
  const int w = threadIdx.x >> 6, l = threadIdx.x & 63;
  const int r = b * 4 + w;
  if (r >= d.rows) return;
  float s = dot_bf(d.M + (size_t)r * d.ld, d.x, d.dot, l);
  s = wave_red(s);
  if (l == 0) d.y[r] = s;
}

__global__ void init_p(float* p) {
  const int i = blockIdx.x * 256 + threadIdx.x;
  if (i < 5120) p[i] = (i < 5096) ? 1.f : 0.f;  // p_out rows 1000..1023 = 0
}

// Single-block deterministic reductions -> inv_sigma[3]
__global__ __launch_bounds__(256) void finalize_sigma(
    const float* __restrict__ p, const float* __restrict__ t,
    const float* __restrict__ cb, float* __restrict__ scal) {
  __shared__ float red[256];
  __shared__ float sres[9];
  const int segs[9][2] = {{0, 2048},    {2048, 2048}, {4096, 1024},
                          {0, 1024},    {1024, 2048}, {3072, 2048},
                          {0, 2048},    {2048, 2048}, {4096, 1024}};
  const float* bases[3] = {p, t, cb};
  for (int s = 0; s < 9; ++s) {
    const float* src = bases[s / 3] + segs[s][0];
    const int len = segs[s][1];
    float acc = 0.f;
    for (int i = threadIdx.x; i < len; i += 256) {
      const float v = src[i];
      acc += (s < 6) ? v * v : v;
    }
    red[threadIdx.x] = acc;
    __syncthreads();
    for (int st = 128; st; st >>= 1) {
      if (threadIdx.x < st) red[threadIdx.x] += red[threadIdx.x + st];
      __syncthreads();
    }
    if (threadIdx.x == 0) sres[s] = red[0];
    __syncthreads();
  }
  if (threadIdx.x == 0) {
    const float eps = 1e-12f;
    for (int m = 0; m < 3; ++m) {
      const float np = sqrtf(sres[m]);
      const float nt = sqrtf(sres[3 + m]);
      const float sig = sres[6 + m] / ((np + eps) * (nt + eps));
      scal[m] = 1.0f / sig;
    }
  }
}

// fp32 -> bf16 (x only)
__global__ __launch_bounds__(256) void f32_to_bf16_pad(
    const float* __restrict__ src, unsigned short* __restrict__ dst,
    long realTotal, long total) {
  const long idx = ((long)blockIdx.x * 256 + threadIdx.x) * 4;
  if (idx >= total) return;
  ushort4 o;
  if (idx < realTotal) {
    const float4 v = *(const float4*)(src + idx);
    o.x = f2bf(v.x); o.y = f2bf(v.y); o.z = f2bf(v.z); o.w = f2bf(v.w);
  } else {
    o.x = o.y = o.z = o.w = 0;
  }
  *(ushort4*)(dst + idx) = o;
}

// ---------------------------------------------------------------------------
extern "C" void kernel_launch(void* const* d_in, const int* in_sizes, int n_in,
                              void* d_out, int out_size, void* d_ws,
                              size_t ws_size, hipStream_t stream) {
  const float* x = (const float*)d_in[0];
  const float* W_in = (const float*)d_in[1];
  const float* b_in = (const float*)d_in[2];
  const float* W_rec = (const float*)d_in[3];
  const float* b_rec = (const float*)d_in[4];
  const float* W_out = (const float*)d_in[5];
  const float* b_out = (const float*)d_in[6];
  (void)in_sizes; (void)n_in; (void)out_size; (void)ws_size;

  const int B = 4096, DI = 1024, H = 2048, DO = 1000, DOP = 1024;
  const long MB = 1l << 20;

  char* ws = (char*)d_ws;
  unsigned short* Win_bf = (unsigned short*)(ws + 0 * MB);    // [2048][1024] 4MB
  unsigned short* Wrec_bf = (unsigned short*)(ws + 4 * MB);   // [2048][2048] 8MB
  unsigned short* Wout_bf = (unsigned short*)(ws + 12 * MB);  // [1024][2048] 4MB
  unsigned short* x_bf = (unsigned short*)(ws + 16 * MB);     // [4096][1024] 8MB
  // G region (24..40MB) dead after power; xpb aliases it (written at MODE0).
  unsigned short* G_in = (unsigned short*)(ws + 24 * MB);     // [2048][2048] 8MB
  unsigned short* G_rec = (unsigned short*)(ws + 32 * MB);    // [2048][2048] 8MB
  unsigned short* xpb = (unsigned short*)(ws + 24 * MB);      // [4096][2048] 16MB
  // WT region (40..56MB) dead after the final W^T pass; h_a aliases it.
  unsigned short* WT_in_bf = (unsigned short*)(ws + 40 * MB);   // 4MB
  unsigned short* WT_rec_bf = (unsigned short*)(ws + 44 * MB);  // 8MB
  unsigned short* WT_out_bf = (unsigned short*)(ws + 52 * MB);  // 4MB
  unsigned short* h_a = (unsigned short*)(ws + 40 * MB);      // 16MB (alias WT)
  // H region (56..74MB) dead after G-build; h_b aliases 56..72MB.
  unsigned short* H_in = (unsigned short*)(ws + 56 * MB);     // [2048][2048] 8MB
  unsigned short* H_rec = (unsigned short*)(ws + 64 * MB);    // [2048][2048] 8MB
  unsigned short* H_out = (unsigned short*)(ws + 72 * MB);    // [1024][1024] 2MB
  unsigned short* h_b = (unsigned short*)(ws + 56 * MB);      // 16MB (alias H)
  unsigned short* G_out = (unsigned short*)(ws + 74 * MB);    // [1024][1024] 2MB
  float* pvec = (float*)(ws + 76 * MB);
  float* tvec = pvec + 5120;
  float* cbuf = tvec + 5120;
  float* scal = cbuf + 5120;
  float* qvec = scal + 16;

  float* p_in = pvec, *p_rec = pvec + 2048, *p_out = pvec + 4096;
  float* t_in = tvec, *t_rec = tvec + 1024, *t_out = tvec + 3072;
  float* q_in = qvec, *q_rec = qvec + 2048, *q_out = qvec + 4096;

  // 1. Fused convert+transpose for weights; x convert.
  convT_b<<<dim3(DI / 32, H / 32), 256, 0, stream>>>(W_in, Win_bf, WT_in_bf,
                                                     H, DI, H);
  convT_b<<<dim3(H / 32, H / 32), 256, 0, stream>>>(W_rec, Wrec_bf, WT_rec_bf,
                                                    H, H, H);
  convT_b<<<dim3(H / 32, DOP / 32), 256, 0, stream>>>(W_out, Wout_bf,
                                                      WT_out_bf, DOP, H, DO);
  f32_to_bf16_pad<<<4096, 256, 0, stream>>>(x, x_bf, (long)B * DI, (long)B * DI);

  // 2a. H = bf16(W @ W^T); then G = bf16(H @ H^T) = H^2 (H symmetric).
  init_p<<<20, 256, 0, stream>>>(pvec);
  gemm3b<3><<<16 * 16, 256, 0, stream>>>(Win_bf, Win_bf, H, DI, 16, 16,
                                         nullptr, nullptr, nullptr, nullptr,
                                         nullptr, H_in, nullptr, H);
  gemm3b<3><<<16 * 16, 256, 0, stream>>>(Wrec_bf, Wrec_bf, H, H, 16, 16,
                                         nullptr, nullptr, nullptr, nullptr,
                                         nullptr, H_rec, nullptr, H);
  gemm3b<3><<<8 * 8, 256, 0, stream>>>(Wout_bf, Wout_bf, DOP, H, 8, 8,
                                       nullptr, nullptr, nullptr, nullptr,
                                       nullptr, H_out, nullptr, DOP);
  gemm3b<3><<<16 * 16, 256, 0, stream>>>(H_in, H_in, H, H, 16, 16, nullptr,
                                         nullptr, nullptr, nullptr, nullptr,
                                         G_in, nullptr, H);
  gemm3b<3><<<16 * 16, 256, 0, stream>>>(H_rec, H_rec, H, H, 16, 16, nullptr,
                                         nullptr, nullptr, nullptr, nullptr,
                                         G_rec, nullptr, H);
  gemm3b<3><<<8 * 8, 256, 0, stream>>>(H_out, H_out, DOP, DOP, 8, 8, nullptr,
                                       nullptr, nullptr, nullptr, nullptr,
                                       G_out, nullptr, DOP);

  // 2b. 15 passes of u <- G u  (= H^30 u). Ends with u in qvec.
  MatDescB GpA = {G_in, p_in, q_in, 2048, 2048, 2048};
  MatDescB GpB = {G_rec, p_rec, q_rec, 2048, 2048, 2048};
  MatDescB GpC = {G_out, p_out, q_out, 1024, 1024, 1024};
  MatDescB GqA = {G_in, q_in, p_in, 2048, 2048, 2048};
  MatDescB GqB = {G_rec, q_rec, p_rec, 2048, 2048, 2048};
  MatDescB GqC = {G_out, q_out, p_out, 1024, 1024, 1024};
  for (int it = 0; it < 7; ++it) {
    matvec3b<<<1280, 256, 0, stream>>>(GpA, GpB, GpC, 512, 512);
    matvec3b<<<1280, 256, 0, stream>>>(GqA, GqB, GqC, 512, 512);
  }
  matvec3b<<<1280, 256, 0, stream>>>(GpA, GpB, GpC, 512, 512);  // pass 15 -> q
  // final: t = W^T u  (v unnormalized)
  MatDescB B1a = {WT_in_bf, q_in, t_in, 1024, 2048, 2048};
  MatDescB B1b = {WT_rec_bf, q_rec, t_rec, 2048, 2048, 2048};
  MatDescB B1c = {WT_out_bf, q_out, t_out, 2048, 1024, 1024};
  matvec3b<<<1280, 256, 0, stream>>>(B1a, B1b, B1c, 256, 512);

  // 3. sigma via exact fp32 W: c_i = u_i * (row_i(W) . t); then 1/sigma
  MatDesc sa = {W_in, t_in, cbuf, q_in, 2048, 1024, 1024, 2048};
  MatDesc sb = {W_rec, t_rec, cbuf + 2048, q_rec, 2048, 2048, 2048, 2048};
  MatDesc sc = {W_out, t_out, cbuf + 4096, q_out, 1024, 2048, 2048, 1000};
  matvec3<<<1280, 256, 0, stream>>>(sa, sb, sc, 512, 512);
  finalize_sigma<<<1, 256, 0, stream>>>(qvec, tvec, cbuf, scal);

  // 4. xpb = bf16(x @ Win^T * is0 + b_in + b_rec); h1 = tanh(same), fused
  gemm3b<0><<<32 * 16, 256, 0, stream>>>(
      x_bf, Win_bf, H, DI, 32, 16, b_in, b_rec, nullptr, scal + 0, nullptr,
      xpb, h_a, H);

  // 5. 29 recurrent GEMM steps ping-pong
  const unsigned short* hin = h_a;
  unsigned short* hout = h_b;
  for (int s = 2; s <= NSTEPS; ++s) {
    gemm3b<1><<<32 * 16, 256, 0, stream>>>(
        hin, Wrec_bf, H, H, 32, 16, nullptr, nullptr, xpb, scal + 1, nullptr,
        hout, nullptr, H);
    const unsigned short* tmp = hin;
    hin = hout;
    hout = (unsigned short*)tmp;
  }

  // 6. out = h @ Wout^T * is2 + b_out  (N padded to 1024, stores guarded)
  gemm3b<2><<<32 * 8, 256, 0, stream>>>(
      hin, Wout_bf, DOP, H, 32, 8, b_out, nullptr, nullptr, scal + 2,
      (float*)d_out, nullptr, nullptr, DO);
}